// Round 9
// baseline (97.120 us; speedup 1.0000x reference)
//
#include <hip/hip_runtime.h>
#include <hip/hip_bf16.h>

#define HIDDEN 1024
#define HEADS  2560

// GEMM geometry: 128x160 tile, BK=64, grid = (8192/128)*(2560/160) = 1024.
// A-frags loaded global->VGPR (no LDS); B staged in LDS (20KB/tile, dbuf 40KB).
// 8 waves (4M x 2N), per-wave 32x80 = acc[2][5]. ~110 VGPR -> 16 waves/CU.
#define BM 128
#define BN 160
#define BK 64
#define NT (HIDDEN / BK)        // 16 K-tiles
#define BBYT (BN * BK * 2)      // 20480 ; dbuf = 40960

typedef float  f32x4  __attribute__((ext_vector_type(4)));
typedef __bf16 bf16x8 __attribute__((ext_vector_type(8)));
typedef __bf16 bf16x4 __attribute__((ext_vector_type(4)));

__device__ __forceinline__ void gload_lds16(const void* g, void* l) {
    __builtin_amdgcn_global_load_lds(
        (const __attribute__((address_space(1))) unsigned int*)g,
        (__attribute__((address_space(3))) unsigned int*)l, 16, 0, 0);
}
// Swizzle: logical byte x (128B rows) lives at x ^ ((row&7)<<4). Involution;
// bits 7+ (row) unchanged.
__device__ __forceinline__ unsigned swz(unsigned x) {
    return x ^ (((x >> 7) & 7u) << 4);
}

// ---------------------------------------------------------------------------
// Fused pass 1: blocks [0,640) transpose W f32[K][N] -> Wt bf16[N][K];
//               blocks [640,...) convert x f32 -> bf16 (row-major preserved).
// ---------------------------------------------------------------------------
__global__ __launch_bounds__(256)
void cvt_all(const float* __restrict__ x, const float* __restrict__ W,
             __bf16* __restrict__ xc, __bf16* __restrict__ Wt, int n8)
{
    if (blockIdx.x < 640) {
        __shared__ __bf16 tile[64][72];
        const int t  = threadIdx.x;
        const int n0 = (blockIdx.x % 40) * 64;
        const int k0 = (blockIdx.x / 40) * 64;

        #pragma unroll
        for (int i = 0; i < 4; ++i) {
            const int k    = (t >> 4) + i * 16;
            const int col4 = (t & 15) * 4;
            const float4 v = *reinterpret_cast<const float4*>(
                W + (size_t)(k0 + k) * HEADS + n0 + col4);
            bf16x4 h;
            h[0] = (__bf16)v.x; h[1] = (__bf16)v.y; h[2] = (__bf16)v.z; h[3] = (__bf16)v.w;
            *reinterpret_cast<bf16x4*>(&tile[k][col4]) = h;
        }
        __syncthreads();
        #pragma unroll
        for (int i = 0; i < 4; ++i) {
            const int n  = (t >> 4) + i * 16;
            const int k4 = (t & 15) * 4;
            bf16x4 h;
            h[0] = tile[k4 + 0][n]; h[1] = tile[k4 + 1][n];
            h[2] = tile[k4 + 2][n]; h[3] = tile[k4 + 3][n];
            *reinterpret_cast<bf16x4*>(Wt + (size_t)(n0 + n) * HIDDEN + k0 + k4) = h;
        }
    } else {
        int idx    = (blockIdx.x - 640) * blockDim.x + threadIdx.x;
        int stride = (gridDim.x - 640) * blockDim.x;
        for (int i = idx; i < n8; i += stride) {
            const float4 a = *reinterpret_cast<const float4*>(x + (size_t)i * 8);
            const float4 b = *reinterpret_cast<const float4*>(x + (size_t)i * 8 + 4);
            bf16x8 h;
            h[0] = (__bf16)a.x; h[1] = (__bf16)a.y; h[2] = (__bf16)a.z; h[3] = (__bf16)a.w;
            h[4] = (__bf16)b.x; h[5] = (__bf16)b.y; h[6] = (__bf16)b.z; h[7] = (__bf16)b.w;
            *reinterpret_cast<bf16x8*>(xc + (size_t)i * 8) = h;
        }
    }
}

// ---------------------------------------------------------------------------
// Pass 2: B-only-LDS pipeline. Per K-tile: {copy A-frag regs cur<-next |
// issue B staging (gload_lds) + A-frag global loads for k+1 | ds_read B +
// MFMA (compiler fine-grained lgkmcnt) | vmcnt(0) covered by full tile |
// one s_barrier}. XCD remap keeps each XCD's A working set (8 slabs = 2MB)
// L2-resident so the A-frag re-reads are L2 hits on a pipe parallel to LDS.
// ---------------------------------------------------------------------------
__global__ __launch_bounds__(512, 4)
void gemm_ar(const __bf16* __restrict__ A, const __bf16* __restrict__ Bt,
             const float* __restrict__ bias, float* __restrict__ out)
{
    __shared__ char lds[2 * BBYT];   // 40 KB (B double-buffer only)

    const int t    = threadIdx.x;
    const int lane = t & 63;
    const int w    = t >> 6;      // 0..7
    const int wr   = w & 3;       // 0..3 : 32-row slab
    const int wc   = w >> 2;      // 0..1 : 80-col slab
    const int lhi  = lane >> 4;   // 0..3
    const int llo  = lane & 15;   // 0..15

    // XCD remap: XCD = bid&7 gets bx in [8*XCD, 8*XCD+8) -> A slabs 2MB,
    // L2-resident; all 16 B-panels stream through L2 from L3 (5MB total).
    const int bid = blockIdx.x;
    const int q   = bid >> 3;
    const int bx  = (bid & 7) * 8 + (q & 7);
    const int by  = q >> 3;
    const int bm0 = bx * BM;
    const int bn0 = by * BN;

    // ---- B staging descriptors (pre-swizzled source, linear LDS dest)
    const unsigned d0 = (unsigned)(t * 16);
    const unsigned L0 = swz(d0);
    const char* bsrc0 = (const char*)Bt + (size_t)(bn0 + (L0 >> 7)) * (HIDDEN * 2) + (L0 & 127);
    const unsigned dt = 16384u + (unsigned)(t * 16);    // tail [16384,20480), t<256
    const unsigned Lt = swz(dt);
    const char* bsrct = (const char*)Bt + (size_t)(bn0 + (Lt >> 7)) * (HIDDEN * 2) + (Lt & 127);
    char* bdst0 = (char*)lds + d0;
    char* bdstt = (char*)lds + dt;

    // ---- A fragment lane pointer: frag (m,kk) of tile k at
    // a_lane + m*32768 + kk*64 + k*128   (row = bm0+wr*32+m*16+llo, col lhi*16)
    const char* a_lane = (const char*)A
        + (size_t)(bm0 + wr * 32 + llo) * (HIDDEN * 2) + lhi * 16;

    // ---- B fragment read offsets (folded XOR -- carry-safe, see R6 bug)
    const unsigned xa = (unsigned)((llo & 7) << 4);
    const unsigned klo[2] = { ((unsigned)(lhi * 16)) ^ xa,
                              ((unsigned)(64 + lhi * 16)) ^ xa };
    const unsigned rowB = (unsigned)(wc * 10240 + llo * 128);

    f32x4 acc[2][5];
    #pragma unroll
    for (int m = 0; m < 2; ++m)
        #pragma unroll
        for (int n = 0; n < 5; ++n)
            acc[m][n] = f32x4{0.f, 0.f, 0.f, 0.f};

    bf16x8 afn[2][2], afc[2][2];   // next / current A-frags (static-indexed)

    // ---- prologue: stage B tile 0 -> buf0; load A-frags tile 0
    gload_lds16(bsrc0,          bdst0);
    gload_lds16(bsrc0 + 131072, bdst0 + 8192);
    if (w < 4) gload_lds16(bsrct, bdstt);
    #pragma unroll
    for (int m = 0; m < 2; ++m)
        #pragma unroll
        for (int kk = 0; kk < 2; ++kk)
            afn[m][kk] = *(const bf16x8*)(a_lane + m * 32768 + kk * 64);
    asm volatile("s_waitcnt vmcnt(0)" ::: "memory");
    __builtin_amdgcn_s_barrier();

    for (int k = 0; k < NT; ++k) {
        const char* buf  = lds + (k & 1) * BBYT;
        const unsigned nb = (unsigned)(((k + 1) & 1) * BBYT);
        const int   koff = (k + 1) * 128;

        // ---- rotate A-frag registers (anti-dep resolved before new loads)
        #pragma unroll
        for (int m = 0; m < 2; ++m)
            #pragma unroll
            for (int kk = 0; kk < 2; ++kk)
                afc[m][kk] = afn[m][kk];

        // ---- early issue: stage B(k+1) + load A-frags(k+1)
        if (k + 1 < NT) {
            gload_lds16(bsrc0 + koff,          bdst0 + nb);
            gload_lds16(bsrc0 + koff + 131072, bdst0 + nb + 8192);
            if (w < 4) gload_lds16(bsrct + koff, bdstt + nb);
            #pragma unroll
            for (int m = 0; m < 2; ++m)
                #pragma unroll
                for (int kk = 0; kk < 2; ++kk)
                    afn[m][kk] = *(const bf16x8*)(a_lane + m * 32768 + kk * 64 + koff);
        }

        // ---- compute: 10 ds_read_b128 + 20 MFMA, compiler-scheduled
        #pragma unroll
        for (int kk = 0; kk < 2; ++kk) {
            bf16x8 bfr[5];
            #pragma unroll
            for (int n = 0; n < 5; ++n)
                bfr[n] = *(const bf16x8*)(buf + rowB + n * 2048 + klo[kk]);
            __builtin_amdgcn_s_setprio(1);
            #pragma unroll
            for (int m = 0; m < 2; ++m)
                #pragma unroll
                for (int n = 0; n < 5; ++n)
                    acc[m][n] = __builtin_amdgcn_mfma_f32_16x16x32_bf16(
                        afc[m][kk], bfr[n], acc[m][n], 0, 0, 0);
            __builtin_amdgcn_s_setprio(0);
        }

        // ---- tile boundary: staged B + A-frag loads had a full tile to land
        asm volatile("s_waitcnt vmcnt(0)" ::: "memory");
        __builtin_amdgcn_s_barrier();
    }

    // ---- epilogue: bias + sigmoid; C/D: col = lane&15, row = (lane>>4)*4+reg
    #pragma unroll
    for (int n = 0; n < 5; ++n) {
        const int col  = bn0 + wc * 80 + n * 16 + llo;
        const float bv = bias[col];
        #pragma unroll
        for (int m = 0; m < 2; ++m) {
            const int row0 = bm0 + wr * 32 + m * 16 + lhi * 4;
            #pragma unroll
            for (int r = 0; r < 4; ++r) {
                const float z = acc[m][n][r] + bv;
                out[(size_t)(row0 + r) * HEADS + col] = __fdividef(1.0f, 1.0f + __expf(-z));
            }
        }
    }
}

// ---------------------------------------------------------------------------
// Fallback (R1 fused kernel) if workspace is too small.
// ---------------------------------------------------------------------------
#define FBM 128
#define FBN 128
#define FBK 32
#define FLDK 40

__global__ __launch_bounds__(256)
void lch_gemm(const float* __restrict__ x, const float* __restrict__ W,
              const float* __restrict__ b, float* __restrict__ out)
{
    __shared__ __bf16 As[FBM][FLDK];
    __shared__ __bf16 Bs[FBN][FLDK];

    const int t   = threadIdx.x;
    const int bm0 = blockIdx.x * FBM;
    const int bn0 = blockIdx.y * FBN;
    const int lane = t & 63;
    const int wid  = t >> 6;
    const int wr   = wid >> 1;
    const int wc   = wid & 1;
    const int lhi  = lane >> 4;
    const int llo  = lane & 15;

    f32x4 acc[4][4];
    #pragma unroll
    for (int i = 0; i < 4; ++i)
        #pragma unroll
        for (int j = 0; j < 4; ++j)
            acc[i][j] = f32x4{0.f, 0.f, 0.f, 0.f};

    const int bn_col  = t & 127;
    const int bk_base = (t >> 7) * 16;

    for (int k0 = 0; k0 < HIDDEN; k0 += FBK) {
        #pragma unroll
        for (int i = 0; i < 4; ++i) {
            const int f   = t + i * 256;
            const int row = f >> 3;
            const int c4  = (f & 7) * 4;
            const float4 v = *reinterpret_cast<const float4*>(
                x + (size_t)(bm0 + row) * HIDDEN + k0 + c4);
            bf16x4 h;
            h[0] = (__bf16)v.x; h[1] = (__bf16)v.y;
            h[2] = (__bf16)v.z; h[3] = (__bf16)v.w;
            *reinterpret_cast<bf16x4*>(&As[row][c4]) = h;
        }
        {
            const float* wp = W + (size_t)(k0 + bk_base) * HEADS + bn0 + bn_col;
            bf16x8 h0, h1;
            #pragma unroll
            for (int i = 0; i < 8; ++i) h0[i] = (__bf16)wp[(size_t)i * HEADS];
            #pragma unroll
            for (int i = 0; i < 8; ++i) h1[i] = (__bf16)wp[(size_t)(i + 8) * HEADS];
            *reinterpret_cast<bf16x8*>(&Bs[bn_col][bk_base])     = h0;
            *reinterpret_cast<bf16x8*>(&Bs[bn_col][bk_base + 8]) = h1;
        }
        __syncthreads();

        bf16x8 af[4], bfr[4];
        #pragma unroll
        for (int i = 0; i < 4; ++i)
            af[i] = *reinterpret_cast<const bf16x8*>(&As[wr * 64 + i * 16 + llo][lhi * 8]);
        #pragma unroll
        for (int j = 0; j < 4; ++j)
            bfr[j] = *reinterpret_cast<const bf16x8*>(&Bs[wc * 64 + j * 16 + llo][lhi * 8]);
        #pragma unroll
        for (int i = 0; i < 4; ++i)
            #pragma unroll
            for (int j = 0; j < 4; ++j)
                acc[i][j] = __builtin_amdgcn_mfma_f32_16x16x32_bf16(
                    af[i], bfr[j], acc[i][j], 0, 0, 0);
        __syncthreads();
    }

    #pragma unroll
    for (int j = 0; j < 4; ++j) {
        const int col  = bn0 + wc * 64 + j * 16 + llo;
        const float bv = b[col];
        #pragma unroll
        for (int i = 0; i < 4; ++i) {
            const int row0 = bm0 + wr * 64 + i * 16 + lhi * 4;
            #pragma unroll
            for (int r = 0; r < 4; ++r) {
                const float z = acc[i][j][r] + bv;
                out[(size_t)(row0 + r) * HEADS + col] = 1.0f / (1.0f + __expf(-z));
            }
        }
    }
}

extern "C" void kernel_launch(void* const* d_in, const int* in_sizes, int n_in,
                              void* d_out, int out_size, void* d_ws, size_t ws_size,
                              hipStream_t stream) {
    const float* x = (const float*)d_in[0];
    const float* W = (const float*)d_in[1];
    const float* b = (const float*)d_in[2];
    float* out     = (float*)d_out;

    const int M = in_sizes[0] / HIDDEN;   // 8192

    const size_t xc_bytes = (size_t)M * HIDDEN * sizeof(__bf16);
    const size_t wt_bytes = (size_t)HEADS * HIDDEN * sizeof(__bf16);

    if (ws_size >= xc_bytes + wt_bytes && (M % BM) == 0) {
        __bf16* xc = (__bf16*)d_ws;
        __bf16* Wt = (__bf16*)((char*)d_ws + xc_bytes);

        cvt_all<<<640 + 2048, 256, 0, stream>>>(x, W, xc, Wt, M * HIDDEN / 8);

        const int nwg = (M / BM) * (HEADS / BN);   // 64 * 16 = 1024
        gemm_ar<<<nwg, 512, 0, stream>>>(xc, Wt, b, out);
    } else {
        dim3 grid(M / FBM, HEADS / FBN);
        lch_gemm<<<grid, dim3(256), 0, stream>>>(x, W, b, out);
    }
}

// Round 10
// 66.346 us; speedup vs baseline: 1.4638x; 1.4638x over previous
//
#include <hip/hip_runtime.h>
#include <hip/hip_bf16.h>

#define HIDDEN 1024
#define HEADS  2560

// GEMM geometry: 128x160 tile, BK=64, grid = (8192/128)*(2560/160) = 64*16 = 1024
// LDS: 2 buffers * (16384 + 20480) = 73728 B -> 2 blocks/CU, 16 waves/CU.
// This is the optimum of the {dbuf<=80KB, BK=64, M%BM=0, 2560%BN=0} family:
// per-wave 32x80 maximizes RC/(R+C) at VGPR<=64 (4 waves/SIMD).
#define BM 128
#define BN 160
#define BK 64
#define NT (HIDDEN / BK)        // 16 K-tiles
#define ABYT (BM * BK * 2)      // 16384
#define BBYT (BN * BK * 2)      // 20480
#define BUFSZ (ABYT + BBYT)     // 36864

typedef float  f32x4  __attribute__((ext_vector_type(4)));
typedef __bf16 bf16x8 __attribute__((ext_vector_type(8)));
typedef __bf16 bf16x4 __attribute__((ext_vector_type(4)));

__device__ __forceinline__ void gload_lds16(const void* g, void* l) {
    __builtin_amdgcn_global_load_lds(
        (const __attribute__((address_space(1))) unsigned int*)g,
        (__attribute__((address_space(3))) unsigned int*)l, 16, 0, 0);
}
// Swizzle: logical byte x (128B rows) lives at x ^ ((row&7)<<4). Involution.
__device__ __forceinline__ unsigned swz(unsigned x) {
    return x ^ (((x >> 7) & 7u) << 4);
}

// ---------------------------------------------------------------------------
// Fused pass 1: blocks [0,640) transpose W f32[K][N] -> Wt bf16[N][K];
//               blocks [640,...) convert x f32 -> bf16.
// ---------------------------------------------------------------------------
__global__ __launch_bounds__(256)
void cvt_all(const float* __restrict__ x, const float* __restrict__ W,
             __bf16* __restrict__ xc, __bf16* __restrict__ Wt, int n8)
{
    if (blockIdx.x < 640) {
        __shared__ __bf16 tile[64][72];
        const int t  = threadIdx.x;
        const int n0 = (blockIdx.x % 40) * 64;
        const int k0 = (blockIdx.x / 40) * 64;

        #pragma unroll
        for (int i = 0; i < 4; ++i) {
            const int k    = (t >> 4) + i * 16;
            const int col4 = (t & 15) * 4;
            const float4 v = *reinterpret_cast<const float4*>(
                W + (size_t)(k0 + k) * HEADS + n0 + col4);
            bf16x4 h;
            h[0] = (__bf16)v.x; h[1] = (__bf16)v.y; h[2] = (__bf16)v.z; h[3] = (__bf16)v.w;
            *reinterpret_cast<bf16x4*>(&tile[k][col4]) = h;
        }
        __syncthreads();
        #pragma unroll
        for (int i = 0; i < 4; ++i) {
            const int n  = (t >> 4) + i * 16;
            const int k4 = (t & 15) * 4;
            bf16x4 h;
            h[0] = tile[k4 + 0][n]; h[1] = tile[k4 + 1][n];
            h[2] = tile[k4 + 2][n]; h[3] = tile[k4 + 3][n];
            *reinterpret_cast<bf16x4*>(Wt + (size_t)(n0 + n) * HIDDEN + k0 + k4) = h;
        }
    } else {
        int idx    = (blockIdx.x - 640) * blockDim.x + threadIdx.x;
        int stride = (gridDim.x - 640) * blockDim.x;
        for (int i = idx; i < n8; i += stride) {
            const float4 a = *reinterpret_cast<const float4*>(x + (size_t)i * 8);
            const float4 b = *reinterpret_cast<const float4*>(x + (size_t)i * 8 + 4);
            bf16x8 h;
            h[0] = (__bf16)a.x; h[1] = (__bf16)a.y; h[2] = (__bf16)a.z; h[3] = (__bf16)a.w;
            h[4] = (__bf16)b.x; h[5] = (__bf16)b.y; h[6] = (__bf16)b.z; h[7] = (__bf16)b.w;
            *reinterpret_cast<bf16x8*>(xc + (size_t)i * 8) = h;
        }
    }
}

// ---------------------------------------------------------------------------
// Pass 2: R7 delockstep pipeline + T5 setprio. Per K-tile: {issue staging for
// k+1 | ds_read+MFMA with setprio(1) around each MFMA cluster | vmcnt(0)
// covered by full tile | one s_barrier}. Waves between barriers are at
// distinct roles (staging/reading/MFMA) -> setprio has something to arbitrate.
// ---------------------------------------------------------------------------
__global__ __launch_bounds__(512, 4)
void gemm_dl3(const __bf16* __restrict__ A, const __bf16* __restrict__ Bt,
              const float* __restrict__ bias, float* __restrict__ out)
{
    __shared__ char lds[2 * BUFSZ];

    const int t    = threadIdx.x;
    const int lane = t & 63;
    const int w    = t >> 6;      // 0..7
    const int wr   = w & 3;       // 0..3 : 32-row slab
    const int wc   = w >> 2;      // 0..1 : 80-col slab
    const int lhi  = lane >> 4;   // 0..3
    const int llo  = lane & 15;   // 0..15

    // XCD mapping: XCD(bid)=bid%8 gets by in {2i,2i+1} -> 2 B-panels (640KB) per L2
    const int bid = blockIdx.x;
    const int by  = (bid & 7) * 2 + ((bid >> 3) & 1);
    const int bx  = bid >> 4;
    const int bm0 = bx * BM;
    const int bn0 = by * BN;

    // ---- staging descriptors (pre-swizzled global source, linear LDS dest)
    const unsigned d0 = (unsigned)(t * 16);
    const unsigned L0 = swz(d0);
    const char* asrc0 = (const char*)A  + (size_t)(bm0 + (L0 >> 7)) * (HIDDEN * 2) + (L0 & 127);
    const char* bsrc0 = (const char*)Bt + (size_t)(bn0 + (L0 >> 7)) * (HIDDEN * 2) + (L0 & 127);
    const unsigned dt = 16384u + (unsigned)(t * 16);    // B tail, staged by w<4
    const unsigned Lt = swz(dt);
    const char* bsrct = (const char*)Bt + (size_t)(bn0 + (Lt >> 7)) * (HIDDEN * 2) + (Lt & 127);

    char* adst0 = (char*)lds + d0;               // A region [0, 16384)
    char* bdst0 = (char*)lds + ABYT + d0;        // B region [16384, 36864)
    char* bdstt = (char*)lds + ABYT + dt;

    // ---- fragment read offsets. XOR folded BEFORE any add: klo[kk] < 128,
    // so rowbase + klo[kk] never carries into row bits (the R6 bug).
    const unsigned xa = (unsigned)((llo & 7) << 4);
    const unsigned klo[2] = { ((unsigned)(lhi * 16)) ^ xa,
                              ((unsigned)(64 + lhi * 16)) ^ xa };
    const unsigned rowA = (unsigned)((wr * 32 + llo) * 128);
    const unsigned rowB = (unsigned)ABYT + (unsigned)((wc * 80 + llo) * 128);

    f32x4 acc[2][5];
    #pragma unroll
    for (int m = 0; m < 2; ++m)
        #pragma unroll
        for (int n = 0; n < 5; ++n)
            acc[m][n] = f32x4{0.f, 0.f, 0.f, 0.f};

    // ---- prologue: stage T0 -> buf0
    gload_lds16(asrc0,          adst0);
    gload_lds16(asrc0 + 131072, adst0 + 8192);
    gload_lds16(bsrc0,          bdst0);
    gload_lds16(bsrc0 + 131072, bdst0 + 8192);
    if (w < 4) gload_lds16(bsrct, bdstt);
    asm volatile("s_waitcnt vmcnt(0)" ::: "memory");
    __builtin_amdgcn_s_barrier();

    for (int k = 0; k < NT; ++k) {
        const char* buf  = lds + (k & 1) * BUFSZ;
        const unsigned nb = (unsigned)(((k + 1) & 1) * BUFSZ);
        const int   koff = (k + 1) * 128;   // byte advance into next K-tile

        // ---- early issue: stage tile k+1 (a full tile of latency cover)
        if (k + 1 < NT) {
            gload_lds16(asrc0 + koff,          adst0 + nb);
            gload_lds16(asrc0 + koff + 131072, adst0 + nb + 8192);
            gload_lds16(bsrc0 + koff,          bdst0 + nb);
            gload_lds16(bsrc0 + koff + 131072, bdst0 + nb + 8192);
            if (w < 4) gload_lds16(bsrct + koff, bdstt + nb);
        }

        // ---- compute: 14 ds_read_b128 + 20 MFMA; setprio favors the wave
        // that has reached its MFMA cluster over waves still issuing memory.
        #pragma unroll
        for (int kk = 0; kk < 2; ++kk) {
            bf16x8 af[2], bfr[5];
            #pragma unroll
            for (int m = 0; m < 2; ++m)
                af[m]  = *(const bf16x8*)(buf + rowA + m * 2048 + klo[kk]);
            #pragma unroll
            for (int n = 0; n < 5; ++n)
                bfr[n] = *(const bf16x8*)(buf + rowB + n * 2048 + klo[kk]);
            __builtin_amdgcn_s_setprio(1);
            #pragma unroll
            for (int m = 0; m < 2; ++m)
                #pragma unroll
                for (int n = 0; n < 5; ++n)
                    acc[m][n] = __builtin_amdgcn_mfma_f32_16x16x32_bf16(
                        af[m], bfr[n], acc[m][n], 0, 0, 0);
            __builtin_amdgcn_s_setprio(0);
        }

        // ---- tile boundary
        asm volatile("s_waitcnt vmcnt(0)" ::: "memory");
        __builtin_amdgcn_s_barrier();
    }

    // ---- epilogue: bias + sigmoid; C/D: col = lane&15, row = (lane>>4)*4+reg
    #pragma unroll
    for (int n = 0; n < 5; ++n) {
        const int col  = bn0 + wc * 80 + n * 16 + llo;
        const float bv = bias[col];
        #pragma unroll
        for (int m = 0; m < 2; ++m) {
            const int row0 = bm0 + wr * 32 + m * 16 + lhi * 4;
            #pragma unroll
            for (int r = 0; r < 4; ++r) {
                const float z = acc[m][n][r] + bv;
                out[(size_t)(row0 + r) * HEADS + col] = __fdividef(1.0f, 1.0f + __expf(-z));
            }
        }
    }
}

// ---------------------------------------------------------------------------
// Fallback (R1 fused kernel) if workspace is too small.
// ---------------------------------------------------------------------------
#define FBM 128
#define FBN 128
#define FBK 32
#define FLDK 40

__global__ __launch_bounds__(256)
void lch_gemm(const float* __restrict__ x, const float* __restrict__ W,
              const float* __restrict__ b, float* __restrict__ out)
{
    __shared__ __bf16 As[FBM][FLDK];
    __shared__ __bf16 Bs[FBN][FLDK];

    const int t   = threadIdx.x;
    const int bm0 = blockIdx.x * FBM;
    const int bn0 = blockIdx.y * FBN;
    const int lane = t & 63;
    const int wid  = t >> 6;
    const int wr   = wid >> 1;
    const int wc   = wid & 1;
    const int lhi  = lane >> 4;
    const int llo  = lane & 15;

    f32x4 acc[4][4];
    #pragma unroll
    for (int i = 0; i < 4; ++i)
        #pragma unroll
        for (int j = 0; j < 4; ++j)
            acc[i][j] = f32x4{0.f, 0.f, 0.f, 0.f};

    const int bn_col  = t & 127;
    const int bk_base = (t >> 7) * 16;

    for (int k0 = 0; k0 < HIDDEN; k0 += FBK) {
        #pragma unroll
        for (int i = 0; i < 4; ++i) {
            const int f   = t + i * 256;
            const int row = f >> 3;
            const int c4  = (f & 7) * 4;
            const float4 v = *reinterpret_cast<const float4*>(
                x + (size_t)(bm0 + row) * HIDDEN + k0 + c4);
            bf16x4 h;
            h[0] = (__bf16)v.x; h[1] = (__bf16)v.y;
            h[2] = (__bf16)v.z; h[3] = (__bf16)v.w;
            *reinterpret_cast<bf16x4*>(&As[row][c4]) = h;
        }
        {
            const float* wp = W + (size_t)(k0 + bk_base) * HEADS + bn0 + bn_col;
            bf16x8 h0, h1;
            #pragma unroll
            for (int i = 0; i < 8; ++i) h0[i] = (__bf16)wp[(size_t)i * HEADS];
            #pragma unroll
            for (int i = 0; i < 8; ++i) h1[i] = (__bf16)wp[(size_t)(i + 8) * HEADS];
            *reinterpret_cast<bf16x8*>(&Bs[bn_col][bk_base])     = h0;
            *reinterpret_cast<bf16x8*>(&Bs[bn_col][bk_base + 8]) = h1;
        }
        __syncthreads();

        bf16x8 af[4], bfr[4];
        #pragma unroll
        for (int i = 0; i < 4; ++i)
            af[i] = *reinterpret_cast<const bf16x8*>(&As[wr * 64 + i * 16 + llo][lhi * 8]);
        #pragma unroll
        for (int j = 0; j < 4; ++j)
            bfr[j] = *reinterpret_cast<const bf16x8*>(&Bs[wc * 64 + j * 16 + llo][lhi * 8]);
        #pragma unroll
        for (int i = 0; i < 4; ++i)
            #pragma unroll
            for (int j = 0; j < 4; ++j)
                acc[i][j] = __builtin_amdgcn_mfma_f32_16x16x32_bf16(
                    af[i], bfr[j], acc[i][j], 0, 0, 0);
        __syncthreads();
    }

    #pragma unroll
    for (int j = 0; j < 4; ++j) {
        const int col  = bn0 + wc * 64 + j * 16 + llo;
        const float bv = b[col];
        #pragma unroll
        for (int i = 0; i < 4; ++i) {
            const int row0 = bm0 + wr * 64 + i * 16 + lhi * 4;
            #pragma unroll
            for (int r = 0; r < 4; ++r) {
                const float z = acc[i][j][r] + bv;
                out[(size_t)(row0 + r) * HEADS + col] = 1.0f / (1.0f + __expf(-z));
            }
        }
    }
}

extern "C" void kernel_launch(void* const* d_in, const int* in_sizes, int n_in,
                              void* d_out, int out_size, void* d_ws, size_t ws_size,
                              hipStream_t stream) {
    const float* x = (const float*)d_in[0];
    const float* W = (const float*)d_in[1];
    const float* b = (const float*)d_in[2];
    float* out     = (float*)d_out;

    const int M = in_sizes[0] / HIDDEN;   // 8192

    const size_t xc_bytes = (size_t)M * HIDDEN * sizeof(__bf16);
    const size_t wt_bytes = (size_t)HEADS * HIDDEN * sizeof(__bf16);

    if (ws_size >= xc_bytes + wt_bytes && (M % BM) == 0) {
        __bf16* xc = (__bf16*)d_ws;
        __bf16* Wt = (__bf16*)((char*)d_ws + xc_bytes);

        cvt_all<<<640 + 2048, 256, 0, stream>>>(x, W, xc, Wt, M * HIDDEN / 8);

        const int nwg = (M / BM) * (HEADS / BN);   // 64 * 16 = 1024
        gemm_dl3<<<nwg, 512, 0, stream>>>(xc, Wt, b, out);
    } else {
        dim3 grid(M / FBM, HEADS / FBN);
        lch_gemm<<<grid, dim3(256), 0, stream>>>(x, W, b, out);
    }
}